// Round 4
// baseline (341.864 us; speedup 1.0000x reference)
//
#include <hip/hip_runtime.h>
#include <hip/hip_bf16.h>
#include <math.h>

typedef __bf16 bf16x8 __attribute__((ext_vector_type(8)));
typedef __bf16 bf16x4 __attribute__((ext_vector_type(4)));
typedef __bf16 bf16x2 __attribute__((ext_vector_type(2)));
typedef float f32x4 __attribute__((ext_vector_type(4)));

#define B_SZ 32
#define T_SZ 2048
#define D_SZ 512
#define K_SZ 128
#define TC 32
#define NC 64   // T_SZ / TC

__device__ __forceinline__ float softplus_f(float x){
  return x > 20.f ? x : log1pf(expf(x));
}

// ---------------------------------------------------------------------------
// Kernel 1a: spectral norm power iteration -> writes 1/sigma to workspace.
// ---------------------------------------------------------------------------
__global__ __launch_bounds__(512) void sn_pi(const float* __restrict__ W,
                                             const float* __restrict__ u_sn,
                                             float* __restrict__ sig_inv){
  __shared__ float red[512];
  __shared__ float vsh[512];
  __shared__ float ush[128];
  const int t = threadIdx.x;
  if (t < 128) ush[t] = u_sn[t];
  __syncthreads();
  float t1 = 0.f;
  #pragma unroll 8
  for (int k = 0; k < K_SZ; ++k) t1 += W[k*D_SZ + t] * ush[k];
  red[t] = t1 * t1;
  __syncthreads();
  for (int s = 256; s > 0; s >>= 1){ if (t < s) red[t] += red[t+s]; __syncthreads(); }
  const float n1 = sqrtf(red[0]);
  vsh[t] = t1 / (n1 + 1e-6f);
  __syncthreads();
  float t2 = 0.f;
  if (t < 128){
    const float4* Wr = (const float4*)(W + (size_t)t * D_SZ);
    const float4* vp = (const float4*)vsh;
    #pragma unroll 8
    for (int d = 0; d < D_SZ/4; ++d){
      const float4 a = Wr[d], v = vp[d];
      t2 += a.x*v.x + a.y*v.y + a.z*v.z + a.w*v.w;
    }
  }
  __syncthreads();
  red[t] = (t < 128) ? t2*t2 : 0.f;
  __syncthreads();
  for (int s = 256; s > 0; s >>= 1){ if (t < s) red[t] += red[t+s]; __syncthreads(); }
  if (t == 0){
    const float n2sq = red[0];
    const float sigma = n2sq / (sqrtf(n2sq) + 1e-6f);   // u1 . (W v)
    sig_inv[0] = 1.f / sigma;
  }
}

// ---------------------------------------------------------------------------
// Kernel 1b: scale W by 1/sigma into bf16, row-major. 64 blocks x 256 thr.
// ---------------------------------------------------------------------------
__global__ __launch_bounds__(256) void sn_scale(const float* __restrict__ W,
                                                const float* __restrict__ sig_inv,
                                                __bf16* __restrict__ Wb){
  const float inv = sig_inv[0];
  const int i = blockIdx.x*256 + threadIdx.x;   // 0..16383
  const float4 v = ((const float4*)W)[i];
  bf16x4 o; o[0]=(__bf16)(v.x*inv); o[1]=(__bf16)(v.y*inv);
  o[2]=(__bf16)(v.z*inv); o[3]=(__bf16)(v.w*inv);
  ((bf16x4*)Wb)[i] = o;
}

// ---------------------------------------------------------------------------
// Kernel 2: u = x @ W_sn^T   (M=65536, N=128, K=512), bf16 MFMA, bf16 out.
// BK=32 double-buffered LDS (32 KB total -> 4 blocks/CU = 16 waves/CU, 2x the
// BK=64 version), one barrier per K-iter, register prefetch after the barrier.
// Unit map (fb*64 + ll) is conflict-free for both writes and frag reads
// (consecutive lanes -> consecutive b128 units). K accumulation order is the
// same sequential 32-col chunks as before -> U bitwise identical.
// ---------------------------------------------------------------------------
__global__ __launch_bounds__(256, 4) void gemm_xw(const float* __restrict__ X,
                                                  const __bf16* __restrict__ Wb,
                                                  __bf16* __restrict__ U){
  __shared__ bf16x8 As[2][512];   // 8 KB per buffer
  __shared__ bf16x8 Bs[2][512];
  const int tid = threadIdx.x;
  const int lane = tid & 63;
  const int wid = tid >> 6;
  const int wm = wid >> 1, wn = wid & 1;
  const int rowbase = blockIdx.x * 128;
  const int L15 = lane & 15, Lq = lane >> 4;
  f32x4 acc[4][4] = {};

  // staging: thread covers rows rowA + 64r (r=0,1), col group cg (8 cols)
  const int rowA = tid >> 2;      // 0..63
  const int cg   = tid & 3;       // 0..3
  const int colo = cg * 8;
  int pidx[2];
  #pragma unroll
  for (int r = 0; r < 2; ++r){
    const int row = rowA + 64*r;
    pidx[r] = (row >> 4)*64 + ((row & 15) | (cg << 4));
  }
  const float* Xb  = X  + (size_t)(rowbase + rowA)*D_SZ + colo;
  const __bf16* Bb = Wb + (size_t)rowA*D_SZ + colo;

  float4 va[2][2];
  bf16x8 wreg[2];
  #pragma unroll
  for (int r = 0; r < 2; ++r){
    const float4* q = (const float4*)(Xb + (size_t)(64*r)*D_SZ);
    va[r][0] = q[0]; va[r][1] = q[1];
    wreg[r] = *(const bf16x8*)(Bb + (size_t)(64*r)*D_SZ);
  }

  int pb = 0;
  for (int kk = 0; kk < D_SZ; kk += 32){
    #pragma unroll
    for (int r = 0; r < 2; ++r){
      bf16x8 f;
      f[0]=(__bf16)va[r][0].x; f[1]=(__bf16)va[r][0].y; f[2]=(__bf16)va[r][0].z; f[3]=(__bf16)va[r][0].w;
      f[4]=(__bf16)va[r][1].x; f[5]=(__bf16)va[r][1].y; f[6]=(__bf16)va[r][1].z; f[7]=(__bf16)va[r][1].w;
      As[pb][pidx[r]] = f;
      Bs[pb][pidx[r]] = wreg[r];
    }
    __syncthreads();
    if (kk + 32 < D_SZ){
      #pragma unroll
      for (int r = 0; r < 2; ++r){
        const float4* q = (const float4*)(Xb + (size_t)(64*r)*D_SZ + kk + 32);
        va[r][0] = q[0]; va[r][1] = q[1];
        wreg[r] = *(const bf16x8*)(Bb + (size_t)(64*r)*D_SZ + kk + 32);
      }
    }
    bf16x8 af[4];
    #pragma unroll
    for (int ii = 0; ii < 4; ++ii)
      af[ii] = As[pb][(wm*4+ii)*64 + lane];
    #pragma unroll
    for (int jj = 0; jj < 4; ++jj){
      const bf16x8 bv = Bs[pb][(wn*4+jj)*64 + lane];
      #pragma unroll
      for (int ii = 0; ii < 4; ++ii)
        acc[ii][jj] = __builtin_amdgcn_mfma_f32_16x16x32_bf16(af[ii], bv, acc[ii][jj], 0, 0, 0);
    }
    pb ^= 1;
  }
  // epilogue: C/D layout col = lane&15, row = (lane>>4)*4 + reg (m89-verified)
  #pragma unroll
  for (int ii = 0; ii < 4; ++ii){
    const int m = rowbase + (wm*4+ii)*16 + (Lq << 2);
    #pragma unroll
    for (int jj = 0; jj < 4; ++jj){
      const int n = (wn*4+jj)*16 + L15;
      #pragma unroll
      for (int r = 0; r < 4; ++r)
        U[(size_t)(m + r)*K_SZ + n] = (__bf16)acc[ii][jj][r];
    }
  }
}

// ---------------------------------------------------------------------------
// Kernel 3 (pass A): per-chunk summaries. Thread = (chunk, 1 channel).
// Block = 256 threads = 2 chunks x 128 channels. Grid = (NC/2, B) = 1024
// blocks = 4096 waves = 4 waves/SIMD (2x the channel-pair version).
// Same chunking + per-channel op sequence -> bitwise-identical results.
// ---------------------------------------------------------------------------
__global__ __launch_bounds__(256) void pass_a(
    const float* __restrict__ alpha_mod, const float* __restrict__ omega_mod,
    const __bf16* __restrict__ Uarr, const float* __restrict__ dt,
    const float* __restrict__ tau_mod, const float* __restrict__ s_real,
    const float* __restrict__ s_imag, const float* __restrict__ tau_raw,
    const float* __restrict__ bvec,
    float* __restrict__ sumA, float* __restrict__ sumT,
    float* __restrict__ Zr, float* __restrict__ Zi){
  const int t = threadIdx.x;
  const int ch = t & 127;       // channel 0..127
  const int cl = t >> 7;        // chunk-local 0..1
  const int b = blockIdx.y;
  const int c = blockIdx.x*2 + cl;
  const int t0 = c * TC;
  __shared__ float sdt[2*TC], ssc[2*TC];
  if (t < 2*TC){
    const int tg = blockIdx.x*2*TC + t;
    sdt[t] = dt[b*T_SZ + tg];
    ssc[t] = __expf(tau_mod[b*T_SZ + tg]);
  }
  __syncthreads();
  const float tau = softplus_f(tau_raw[0]) + 1e-3f;
  const float a0 = (softplus_f(s_real[ch]) + 1e-6f)*tau;
  const float w0 = s_imag[ch]*tau;
  const float bk = bvec[ch];
  float zr = 0.f, zs = 0.f, sA = 0.f, sT = 0.f;
  const float* sd = sdt + cl*TC;
  const float* ss = ssc + cl*TC;
  const size_t row = (size_t)(b*T_SZ + t0);
  const float* amp = alpha_mod + row*K_SZ + ch;
  const float* omp = omega_mod + row*K_SZ + ch;
  const __bf16* up = Uarr + row*K_SZ + ch;
  #pragma unroll 8
  for (int i = 0; i < TC; ++i){
    const float am = amp[(size_t)i*K_SZ];
    const float om = omp[(size_t)i*K_SZ];
    const float uv = (float)up[(size_t)i*K_SZ];
    const float scdt = ss[i] * sd[i];
    const float ad = a0 * __expf(am) * scdt;
    const float th = w0 * __expf(om) * scdt;
    const float rho = __expf(-ad);
    float st, ct; __sincosf(th, &st, &ct);
    const float uu = uv + bk;
    const float nr = rho*(zr*ct - zs*st) + uu;
    const float ns = rho*(zr*st + zs*ct);
    zr = nr; zs = ns;
    sA += ad; sT += th;
  }
  const size_t idx = ((size_t)(b*NC + c))*K_SZ + ch;
  sumA[idx] = sA;
  sumT[idx] = sT;
  Zr[idx]   = zr;
  Zi[idx]   = zs;
}

// ---------------------------------------------------------------------------
// Kernel 4 (pass B): wave-parallel Kogge-Stone scan of the chunk summaries.
// One wave per (b, channel): 4096 waves, lane = chunk, 6 shuffle-compose
// steps, exclusive prefix via shfl_up(1). (round-3 proven version)
// ---------------------------------------------------------------------------
__global__ __launch_bounds__(256) void pass_b(
    const float* __restrict__ sumA, const float* __restrict__ sumT,
    const float* __restrict__ Zr, const float* __restrict__ Zi,
    float* __restrict__ Cr, float* __restrict__ Ci){
  const int gwave = (blockIdx.x*256 + threadIdx.x) >> 6;  // 0..4095
  const int lane  = threadIdx.x & 63;
  const int b  = gwave >> 7;         // 128 channels per batch
  const int ch = gwave & 127;
  const size_t i0 = ((size_t)(b*NC) + lane)*128 + ch;
  const float sa = sumA[i0], th = sumT[i0];
  const float r = __expf(-sa);
  float s, c; __sincosf(th, &s, &c);
  float Fr = r*c, Fi = r*s;
  float Ur = Zr[i0], Ui = Zi[i0];
  #pragma unroll
  for (int d = 1; d < 64; d <<= 1){
    const float pFr = __shfl_up(Fr, d, 64);
    const float pFi = __shfl_up(Fi, d, 64);
    const float pUr = __shfl_up(Ur, d, 64);
    const float pUi = __shfl_up(Ui, d, 64);
    if (lane >= d){
      const float nFr = Fr*pFr - Fi*pFi;
      const float nFi = Fr*pFi + Fi*pFr;
      const float nUr = Fr*pUr - Fi*pUi + Ur;
      const float nUi = Fr*pUi + Fi*pUr + Ui;
      Fr = nFr; Fi = nFi; Ur = nUr; Ui = nUi;
    }
  }
  float er = __shfl_up(Ur, 1, 64);
  float ei = __shfl_up(Ui, 1, 64);
  if (lane == 0){ er = 0.f; ei = 0.f; }
  Cr[i0] = er; Ci[i0] = ei;
}

// ---------------------------------------------------------------------------
// Kernel 5 (pass C): replay chunks from carry-in, write [B,T,2K] output.
// Thread = (chunk, 1 channel), same occupancy doubling as pass_a.
// ---------------------------------------------------------------------------
__global__ __launch_bounds__(256) void pass_c(
    const float* __restrict__ alpha_mod, const float* __restrict__ omega_mod,
    const __bf16* __restrict__ Uarr, const float* __restrict__ dt,
    const float* __restrict__ tau_mod, const float* __restrict__ s_real,
    const float* __restrict__ s_imag, const float* __restrict__ tau_raw,
    const float* __restrict__ bvec,
    const float* __restrict__ Cr, const float* __restrict__ Ci,
    float* __restrict__ out){
  const int t = threadIdx.x;
  const int ch = t & 127;
  const int cl = t >> 7;
  const int b = blockIdx.y;
  const int c = blockIdx.x*2 + cl;
  const int t0 = c * TC;
  __shared__ float sdt[2*TC], ssc[2*TC];
  if (t < 2*TC){
    const int tg = blockIdx.x*2*TC + t;
    sdt[t] = dt[b*T_SZ + tg];
    ssc[t] = __expf(tau_mod[b*T_SZ + tg]);
  }
  __syncthreads();
  const float tau = softplus_f(tau_raw[0]) + 1e-3f;
  const float a0 = (softplus_f(s_real[ch]) + 1e-6f)*tau;
  const float w0 = s_imag[ch]*tau;
  const float bk = bvec[ch];
  const size_t cidx = ((size_t)(b*NC + c))*K_SZ + ch;
  float zr = Cr[cidx], zs = Ci[cidx];
  const float* sd = sdt + cl*TC;
  const float* ss = ssc + cl*TC;
  const size_t row = (size_t)(b*T_SZ + t0);
  const float* amp = alpha_mod + row*K_SZ + ch;
  const float* omp = omega_mod + row*K_SZ + ch;
  const __bf16* up = Uarr + row*K_SZ + ch;
  float* outp = out + row*(2*K_SZ) + ch;
  #pragma unroll 8
  for (int i = 0; i < TC; ++i){
    const float am = amp[(size_t)i*K_SZ];
    const float om = omp[(size_t)i*K_SZ];
    const float uv = (float)up[(size_t)i*K_SZ];
    const float scdt = ss[i] * sd[i];
    const float ad = a0 * __expf(am) * scdt;
    const float th = w0 * __expf(om) * scdt;
    const float rho = __expf(-ad);
    float st, ct; __sincosf(th, &st, &ct);
    const float uu = uv + bk;
    const float nr = rho*(zr*ct - zs*st) + uu;
    const float ns = rho*(zr*st + zs*ct);
    zr = nr; zs = ns;
    outp[(size_t)i*(2*K_SZ)]          = zr;
    outp[(size_t)i*(2*K_SZ) + K_SZ]   = zs;
  }
}

// ---------------------------------------------------------------------------
extern "C" void kernel_launch(void* const* d_in, const int* in_sizes, int n_in,
                              void* d_out, int out_size, void* d_ws, size_t ws_size,
                              hipStream_t stream){
  (void)in_sizes; (void)n_in; (void)out_size; (void)ws_size;
  const float* x         = (const float*)d_in[0];
  const float* dt        = (const float*)d_in[1];
  const float* alpha_mod = (const float*)d_in[2];
  const float* omega_mod = (const float*)d_in[3];
  const float* tau_mod   = (const float*)d_in[4];
  const float* s_real    = (const float*)d_in[5];
  const float* s_imag    = (const float*)d_in[6];
  const float* tau_raw   = (const float*)d_in[7];
  const float* W         = (const float*)d_in[8];
  const float* bvec      = (const float*)d_in[9];
  const float* u_sn      = (const float*)d_in[10];
  float* out = (float*)d_out;

  char* w = (char*)d_ws;
  __bf16* Wb = (__bf16*)w;                                  // 128 KiB
  __bf16* U  = (__bf16*)(w + 131072);                       // 16 MiB (bf16 u)
  size_t off = 131072 + (size_t)B_SZ*T_SZ*K_SZ*2;
  const size_t SUMN = (size_t)B_SZ*NC*K_SZ*4;               // 1 MiB each
  float* sumA = (float*)(w + off); off += SUMN;
  float* sumT = (float*)(w + off); off += SUMN;
  float* Zr   = (float*)(w + off); off += SUMN;
  float* Zi   = (float*)(w + off); off += SUMN;
  float* Cr   = (float*)(w + off); off += SUMN;
  float* Ci   = (float*)(w + off); off += SUMN;
  float* sig  = (float*)(w + off); off += 256;

  sn_pi<<<1, 512, 0, stream>>>(W, u_sn, sig);
  sn_scale<<<64, 256, 0, stream>>>(W, sig, Wb);
  gemm_xw<<<(B_SZ*T_SZ)/128, 256, 0, stream>>>(x, Wb, U);
  pass_a<<<dim3(NC/2, B_SZ), 256, 0, stream>>>(alpha_mod, omega_mod, U, dt, tau_mod,
                                               s_real, s_imag, tau_raw, bvec,
                                               sumA, sumT, Zr, Zi);
  pass_b<<<(B_SZ*K_SZ)/4, 256, 0, stream>>>(sumA, sumT, Zr, Zi, Cr, Ci);
  pass_c<<<dim3(NC/2, B_SZ), 256, 0, stream>>>(alpha_mod, omega_mod, U, dt, tau_mod,
                                               s_real, s_imag, tau_raw, bvec,
                                               Cr, Ci, out);
}

// Round 6
// 334.174 us; speedup vs baseline: 1.0230x; 1.0230x over previous
//
#include <hip/hip_runtime.h>
#include <hip/hip_bf16.h>
#include <math.h>

typedef __bf16 bf16x8 __attribute__((ext_vector_type(8)));
typedef __bf16 bf16x4 __attribute__((ext_vector_type(4)));
typedef __bf16 bf16x2 __attribute__((ext_vector_type(2)));
typedef float f32x4 __attribute__((ext_vector_type(4)));

#define B_SZ 32
#define T_SZ 2048
#define D_SZ 512
#define K_SZ 128
#define TC 16
#define NC 128   // T_SZ / TC

__device__ __forceinline__ float softplus_f(float x){
  return x > 20.f ? x : log1pf(expf(x));
}

// ---------------------------------------------------------------------------
// Kernel 1a: spectral norm power iteration -> writes 1/sigma to workspace.
// (round-3 proven version)
// ---------------------------------------------------------------------------
__global__ __launch_bounds__(512) void sn_pi(const float* __restrict__ W,
                                             const float* __restrict__ u_sn,
                                             float* __restrict__ sig_inv){
  __shared__ float red[512];
  __shared__ float vsh[512];
  __shared__ float ush[128];
  const int t = threadIdx.x;
  if (t < 128) ush[t] = u_sn[t];
  __syncthreads();
  float t1 = 0.f;
  #pragma unroll 8
  for (int k = 0; k < K_SZ; ++k) t1 += W[k*D_SZ + t] * ush[k];
  red[t] = t1 * t1;
  __syncthreads();
  for (int s = 256; s > 0; s >>= 1){ if (t < s) red[t] += red[t+s]; __syncthreads(); }
  const float n1 = sqrtf(red[0]);
  vsh[t] = t1 / (n1 + 1e-6f);
  __syncthreads();
  float t2 = 0.f;
  if (t < 128){
    const float4* Wr = (const float4*)(W + (size_t)t * D_SZ);
    const float4* vp = (const float4*)vsh;
    #pragma unroll 8
    for (int d = 0; d < D_SZ/4; ++d){
      const float4 a = Wr[d], v = vp[d];
      t2 += a.x*v.x + a.y*v.y + a.z*v.z + a.w*v.w;
    }
  }
  __syncthreads();
  red[t] = (t < 128) ? t2*t2 : 0.f;
  __syncthreads();
  for (int s = 256; s > 0; s >>= 1){ if (t < s) red[t] += red[t+s]; __syncthreads(); }
  if (t == 0){
    const float n2sq = red[0];
    const float sigma = n2sq / (sqrtf(n2sq) + 1e-6f);   // u1 . (W v)
    sig_inv[0] = 1.f / sigma;
  }
}

// ---------------------------------------------------------------------------
// Kernel 1b: scale W by 1/sigma into bf16, row-major. (round-3 proven)
// ---------------------------------------------------------------------------
__global__ __launch_bounds__(256) void sn_scale(const float* __restrict__ W,
                                                const float* __restrict__ sig_inv,
                                                __bf16* __restrict__ Wb){
  const float inv = sig_inv[0];
  const int i = blockIdx.x*256 + threadIdx.x;   // 0..16383
  const float4 v = ((const float4*)W)[i];
  bf16x4 o; o[0]=(__bf16)(v.x*inv); o[1]=(__bf16)(v.y*inv);
  o[2]=(__bf16)(v.z*inv); o[3]=(__bf16)(v.w*inv);
  ((bf16x4*)Wb)[i] = o;
}

// ---------------------------------------------------------------------------
// Kernel 2: u = x @ W_sn^T   (M=65536, N=128, K=512), bf16 MFMA, bf16 out.
// Double-buffered LDS, one barrier per K-iter, register prefetch of the next
// tile issued right after the barrier. XOR-swizzled LDS chunks.
// (exact round-3/round-0 proven version)
// ---------------------------------------------------------------------------
__global__ __launch_bounds__(256) void gemm_xw(const float* __restrict__ X,
                                               const __bf16* __restrict__ Wb,
                                               __bf16* __restrict__ U){
  __shared__ bf16x8 As[2][1024];   // 32 KB
  __shared__ bf16x8 Bs[2][1024];   // 32 KB
  const int tid = threadIdx.x;
  const int lane = tid & 63;
  const int wid = tid >> 6;
  const int wm = wid >> 1, wn = wid & 1;
  const int rowbase = blockIdx.x * 128;
  const int L15 = lane & 15, Lq = lane >> 4;
  f32x4 acc[4][4] = {};

  const int rowA = tid >> 3;      // 0..31
  const int cg   = tid & 7;
  const int colo = cg * 8;
  int pidx[4];
  #pragma unroll
  for (int r = 0; r < 4; ++r){
    const int row = rowA + 32*r;
    const int fb = ((row >> 4) << 1) | (cg >> 2);
    const int ll = (row & 15) | ((cg & 3) << 4);
    pidx[r] = (fb*64 + ll) ^ cg;
  }
  const float* Xb  = X  + (size_t)(rowbase + rowA)*D_SZ + colo;
  const __bf16* Bb = Wb + (size_t)rowA*D_SZ + colo;

  float4 va[4], vb[4];
  bf16x8 wreg[4];
  #pragma unroll
  for (int r = 0; r < 4; ++r){
    const float4* q = (const float4*)(Xb + (size_t)(32*r)*D_SZ);
    va[r] = q[0]; vb[r] = q[1];
    wreg[r] = *(const bf16x8*)(Bb + (size_t)(32*r)*D_SZ);
  }

  int pb = 0;
  for (int kk = 0; kk < D_SZ; kk += 64){
    #pragma unroll
    for (int r = 0; r < 4; ++r){
      bf16x8 f;
      f[0]=(__bf16)va[r].x; f[1]=(__bf16)va[r].y; f[2]=(__bf16)va[r].z; f[3]=(__bf16)va[r].w;
      f[4]=(__bf16)vb[r].x; f[5]=(__bf16)vb[r].y; f[6]=(__bf16)vb[r].z; f[7]=(__bf16)vb[r].w;
      As[pb][pidx[r]] = f;
      Bs[pb][pidx[r]] = wreg[r];
    }
    __syncthreads();
    if (kk + 64 < D_SZ){
      #pragma unroll
      for (int r = 0; r < 4; ++r){
        const float4* q = (const float4*)(Xb + (size_t)(32*r)*D_SZ + kk + 64);
        va[r] = q[0]; vb[r] = q[1];
        wreg[r] = *(const bf16x8*)(Bb + (size_t)(32*r)*D_SZ + kk + 64);
      }
    }
    #pragma unroll
    for (int s = 0; s < 2; ++s){
      bf16x8 af[4], bfr[4];
      const int swz = (s << 2) | (lane >> 4);
      #pragma unroll
      for (int ii = 0; ii < 4; ++ii){
        const int fb = ((wm*4+ii) << 1) | s;
        af[ii] = As[pb][(fb*64 + lane) ^ swz];
      }
      #pragma unroll
      for (int jj = 0; jj < 4; ++jj){
        const int fb = ((wn*4+jj) << 1) | s;
        bfr[jj] = Bs[pb][(fb*64 + lane) ^ swz];
      }
      #pragma unroll
      for (int ii = 0; ii < 4; ++ii)
        #pragma unroll
        for (int jj = 0; jj < 4; ++jj)
          acc[ii][jj] = __builtin_amdgcn_mfma_f32_16x16x32_bf16(af[ii], bfr[jj], acc[ii][jj], 0, 0, 0);
    }
    pb ^= 1;
  }
  // epilogue: C/D layout col = lane&15, row = (lane>>4)*4 + reg (m89-verified)
  #pragma unroll
  for (int ii = 0; ii < 4; ++ii){
    const int m = rowbase + (wm*4+ii)*16 + (Lq << 2);
    #pragma unroll
    for (int jj = 0; jj < 4; ++jj){
      const int n = (wn*4+jj)*16 + L15;
      #pragma unroll
      for (int r = 0; r < 4; ++r)
        U[(size_t)(m + r)*K_SZ + n] = (__bf16)acc[ii][jj][r];
    }
  }
}

// ---------------------------------------------------------------------------
// Kernel 3 (pass A): per-chunk summaries. Thread = (chunk, 2 k-channels),
// float2 loads (512B/wave/instr). TC=16 -> NC=128 chunks: 2048 blocks? no —
// grid (NC/4=32, B) = 1024 blocks = 4096 waves = 4/SIMD (2x round-3), and
// the serial recurrence chain per thread halves (16 iters).
// Body identical to round-3 pass_a except TC.
// ---------------------------------------------------------------------------
__global__ __launch_bounds__(256) void pass_a(
    const float* __restrict__ alpha_mod, const float* __restrict__ omega_mod,
    const __bf16* __restrict__ Uarr, const float* __restrict__ dt,
    const float* __restrict__ tau_mod, const float* __restrict__ s_real,
    const float* __restrict__ s_imag, const float* __restrict__ tau_raw,
    const float* __restrict__ bvec,
    float2* __restrict__ sumA, float2* __restrict__ sumT,
    float2* __restrict__ Zr, float2* __restrict__ Zi){
  const int t = threadIdx.x;
  const int kh = t & 63;        // k-pair index: k = kh*2, kh*2+1
  const int cl = t >> 6;        // chunk-local 0..3
  const int b = blockIdx.y;
  const int c = blockIdx.x*4 + cl;
  const int t0 = c * TC;
  __shared__ float sdt[4*TC], ssc[4*TC];
  if (t < 4*TC){
    const int tg = blockIdx.x*4*TC + t;
    sdt[t] = dt[b*T_SZ + tg];
    ssc[t] = __expf(tau_mod[b*T_SZ + tg]);
  }
  __syncthreads();
  const float tau = softplus_f(tau_raw[0]) + 1e-3f;
  const float2 sr = ((const float2*)s_real)[kh];
  const float2 si = ((const float2*)s_imag)[kh];
  const float2 bk = ((const float2*)bvec)[kh];
  const float a0[2] = {(softplus_f(sr.x)+1e-6f)*tau, (softplus_f(sr.y)+1e-6f)*tau};
  const float w0[2] = {si.x*tau, si.y*tau};
  float zr[2]={0,0}, zs[2]={0,0}, sA[2]={0,0}, sT[2]={0,0};
  const float* sd = sdt + cl*TC;
  const float* ss = ssc + cl*TC;
  const size_t row = (size_t)(b*T_SZ + t0);
  const float2* amp = (const float2*)(alpha_mod + row*K_SZ) + kh;
  const float2* omp = (const float2*)(omega_mod + row*K_SZ) + kh;
  const bf16x2* up  = (const bf16x2*)(Uarr + row*K_SZ) + kh;
  #pragma unroll 8
  for (int i = 0; i < TC; ++i){
    const float2 am = amp[(size_t)i*64];
    const float2 om = omp[(size_t)i*64];
    const bf16x2 u2 = up[(size_t)i*64];
    const float scdt = ss[i] * sd[i];
    #pragma unroll
    for (int j = 0; j < 2; ++j){
      const float ad = a0[j] * __expf(j ? am.y : am.x) * scdt;
      const float th = w0[j] * __expf(j ? om.y : om.x) * scdt;
      const float rho = __expf(-ad);
      float st, ct; __sincosf(th, &st, &ct);
      const float uu = (float)u2[j] + (j ? bk.y : bk.x);
      const float nr = rho*(zr[j]*ct - zs[j]*st) + uu;
      const float ns = rho*(zr[j]*st + zs[j]*ct);
      zr[j] = nr; zs[j] = ns;
      sA[j] += ad; sT[j] += th;
    }
  }
  const size_t idx = ((size_t)(b*NC + c))*64 + kh;
  sumA[idx] = make_float2(sA[0], sA[1]);
  sumT[idx] = make_float2(sT[0], sT[1]);
  Zr[idx]   = make_float2(zr[0], zr[1]);
  Zi[idx]   = make_float2(zs[0], zs[1]);
}

// ---------------------------------------------------------------------------
// Kernel 4 (pass B): wave-parallel Kogge-Stone scan, NC=128. Lane l owns
// chunks 2l, 2l+1: serial pair-compose, 6 shuffle-compose steps, exclusive
// fixup for both chunks. (round-2 proven version, absmax 0.0625)
// ---------------------------------------------------------------------------
__global__ __launch_bounds__(256) void pass_b(
    const float* __restrict__ sumA, const float* __restrict__ sumT,
    const float* __restrict__ Zr, const float* __restrict__ Zi,
    float* __restrict__ Cr, float* __restrict__ Ci){
  const int gwave = (blockIdx.x*256 + threadIdx.x) >> 6;  // 0..4095
  const int lane  = threadIdx.x & 63;
  const int b  = gwave >> 7;         // 128 channels per batch
  const int ch = gwave & 127;        // channel = kh*2 + j
  const size_t i0 = ((size_t)(b*NC) + lane*2)*128 + ch;
  const size_t i1 = i0 + 128;
  const float sa0 = sumA[i0], sa1 = sumA[i1];
  const float th0 = sumT[i0], th1 = sumT[i1];
  const float ur0 = Zr[i0],   ur1 = Zr[i1];
  const float ui0 = Zi[i0],   ui1 = Zi[i1];
  const float r0 = __expf(-sa0), r1 = __expf(-sa1);
  float s0, cc0, s1, cc1;
  __sincosf(th0, &s0, &cc0); __sincosf(th1, &s1, &cc1);
  const float a0r = r0*cc0, a0i = r0*s0;
  const float a1r = r1*cc1, a1i = r1*s1;
  // lane composite F = f1 ∘ f0 : a = a1*a0, u = a1*u0 + u1
  float Fr = a1r*a0r - a1i*a0i;
  float Fi = a1r*a0i + a1i*a0r;
  float Ur = a1r*ur0 - a1i*ui0 + ur1;
  float Ui = a1r*ui0 + a1i*ur0 + ui1;
  #pragma unroll
  for (int d = 1; d < 64; d <<= 1){
    const float pFr = __shfl_up(Fr, d, 64);
    const float pFi = __shfl_up(Fi, d, 64);
    const float pUr = __shfl_up(Ur, d, 64);
    const float pUi = __shfl_up(Ui, d, 64);
    if (lane >= d){
      const float nFr = Fr*pFr - Fi*pFi;
      const float nFi = Fr*pFi + Fi*pFr;
      const float nUr = Fr*pUr - Fi*pUi + Ur;
      const float nUi = Fr*pUi + Fi*pUr + Ui;
      Fr = nFr; Fi = nFi; Ur = nUr; Ui = nUi;
    }
  }
  // exclusive prefix for chunk 2l = inclusive U of lane l-1 (0 for lane 0)
  float e0r = __shfl_up(Ur, 1, 64);
  float e0i = __shfl_up(Ui, 1, 64);
  if (lane == 0){ e0r = 0.f; e0i = 0.f; }
  // exclusive for chunk 2l+1 = f_{2l}(e0)
  const float e1r = a0r*e0r - a0i*e0i + ur0;
  const float e1i = a0r*e0i + a0i*e0r + ui0;
  Cr[i0] = e0r; Ci[i0] = e0i;
  Cr[i1] = e1r; Ci[i1] = e1i;
}

// ---------------------------------------------------------------------------
// Kernel 5 (pass C): replay chunks from carry-in, write [B,T,2K] output.
// Body identical to round-3 pass_c except TC=16 (same occupancy doubling).
// ---------------------------------------------------------------------------
__global__ __launch_bounds__(256) void pass_c(
    const float* __restrict__ alpha_mod, const float* __restrict__ omega_mod,
    const __bf16* __restrict__ Uarr, const float* __restrict__ dt,
    const float* __restrict__ tau_mod, const float* __restrict__ s_real,
    const float* __restrict__ s_imag, const float* __restrict__ tau_raw,
    const float* __restrict__ bvec,
    const float2* __restrict__ Cr, const float2* __restrict__ Ci,
    float* __restrict__ out){
  const int t = threadIdx.x;
  const int kh = t & 63;
  const int cl = t >> 6;
  const int b = blockIdx.y;
  const int c = blockIdx.x*4 + cl;
  const int t0 = c * TC;
  __shared__ float sdt[4*TC], ssc[4*TC];
  if (t < 4*TC){
    const int tg = blockIdx.x*4*TC + t;
    sdt[t] = dt[b*T_SZ + tg];
    ssc[t] = __expf(tau_mod[b*T_SZ + tg]);
  }
  __syncthreads();
  const float tau = softplus_f(tau_raw[0]) + 1e-3f;
  const float2 sr = ((const float2*)s_real)[kh];
  const float2 si = ((const float2*)s_imag)[kh];
  const float2 bk = ((const float2*)bvec)[kh];
  const float a0[2] = {(softplus_f(sr.x)+1e-6f)*tau, (softplus_f(sr.y)+1e-6f)*tau};
  const float w0[2] = {si.x*tau, si.y*tau};
  const size_t cidx = ((size_t)(b*NC + c))*64 + kh;
  const float2 cr = Cr[cidx], cim = Ci[cidx];
  float zr[2] = {cr.x, cr.y}, zs[2] = {cim.x, cim.y};
  const float* sd = sdt + cl*TC;
  const float* ss = ssc + cl*TC;
  const size_t row = (size_t)(b*T_SZ + t0);
  const float2* amp = (const float2*)(alpha_mod + row*K_SZ) + kh;
  const float2* omp = (const float2*)(omega_mod + row*K_SZ) + kh;
  const bf16x2* up  = (const bf16x2*)(Uarr + row*K_SZ) + kh;
  float2* outC = (float2*)(out + row*(2*K_SZ)) + kh;          // stride 128 float2 per t
  float2* outS = outC + 64;
  #pragma unroll 8
  for (int i = 0; i < TC; ++i){
    const float2 am = amp[(size_t)i*64];
    const float2 om = omp[(size_t)i*64];
    const bf16x2 u2 = up[(size_t)i*64];
    const float scdt = ss[i] * sd[i];
    #pragma unroll
    for (int j = 0; j < 2; ++j){
      const float ad = a0[j] * __expf(j ? am.y : am.x) * scdt;
      const float th = w0[j] * __expf(j ? om.y : om.x) * scdt;
      const float rho = __expf(-ad);
      float st, ct; __sincosf(th, &st, &ct);
      const float uu = (float)u2[j] + (j ? bk.y : bk.x);
      const float nr = rho*(zr[j]*ct - zs[j]*st) + uu;
      const float ns = rho*(zr[j]*st + zs[j]*ct);
      zr[j] = nr; zs[j] = ns;
    }
    outC[(size_t)i*128] = make_float2(zr[0], zr[1]);
    outS[(size_t)i*128] = make_float2(zs[0], zs[1]);
  }
}

// ---------------------------------------------------------------------------
extern "C" void kernel_launch(void* const* d_in, const int* in_sizes, int n_in,
                              void* d_out, int out_size, void* d_ws, size_t ws_size,
                              hipStream_t stream){
  (void)in_sizes; (void)n_in; (void)out_size; (void)ws_size;
  const float* x         = (const float*)d_in[0];
  const float* dt        = (const float*)d_in[1];
  const float* alpha_mod = (const float*)d_in[2];
  const float* omega_mod = (const float*)d_in[3];
  const float* tau_mod   = (const float*)d_in[4];
  const float* s_real    = (const float*)d_in[5];
  const float* s_imag    = (const float*)d_in[6];
  const float* tau_raw   = (const float*)d_in[7];
  const float* W         = (const float*)d_in[8];
  const float* bvec      = (const float*)d_in[9];
  const float* u_sn      = (const float*)d_in[10];
  float* out = (float*)d_out;

  char* w = (char*)d_ws;
  __bf16* Wb = (__bf16*)w;                                  // 128 KiB
  __bf16* U  = (__bf16*)(w + 131072);                       // 16 MiB (bf16 u)
  size_t off = 131072 + (size_t)B_SZ*T_SZ*K_SZ*2;
  const size_t SUMN = (size_t)B_SZ*NC*K_SZ*4;               // 2 MiB each
  float2* sumA = (float2*)(w + off); off += SUMN;
  float2* sumT = (float2*)(w + off); off += SUMN;
  float2* Zr   = (float2*)(w + off); off += SUMN;
  float2* Zi   = (float2*)(w + off); off += SUMN;
  float2* Cr   = (float2*)(w + off); off += SUMN;
  float2* Ci   = (float2*)(w + off); off += SUMN;
  float* sig   = (float*)(w + off);  off += 256;

  sn_pi<<<1, 512, 0, stream>>>(W, u_sn, sig);
  sn_scale<<<64, 256, 0, stream>>>(W, sig, Wb);
  gemm_xw<<<(B_SZ*T_SZ)/128, 256, 0, stream>>>(x, Wb, U);
  pass_a<<<dim3(NC/4, B_SZ), 256, 0, stream>>>(alpha_mod, omega_mod, U, dt, tau_mod,
                                               s_real, s_imag, tau_raw, bvec,
                                               sumA, sumT, Zr, Zi);
  pass_b<<<(B_SZ*K_SZ)/4, 256, 0, stream>>>((const float*)sumA, (const float*)sumT,
                                            (const float*)Zr, (const float*)Zi,
                                            (float*)Cr, (float*)Ci);
  pass_c<<<dim3(NC/4, B_SZ), 256, 0, stream>>>(alpha_mod, omega_mod, U, dt, tau_mod,
                                               s_real, s_imag, tau_raw, bvec,
                                               Cr, Ci, out);
}